// Round 3
// baseline (257.497 us; speedup 1.0000x reference)
//
#include <hip/hip_runtime.h>

typedef __attribute__((ext_vector_type(8))) short bf16x8;
typedef __attribute__((ext_vector_type(4))) float f32x4;

constexpr int NN = 50000;          // nodes
constexpr int NE = 800000;         // edges
constexpr int C1 = 128;            // in/hidden channels
constexpr int C2 = 64;             // out channels
constexpr int NBK = 196;           // dst buckets of 256 nodes
constexpr int EPB = 2048;          // edges per bin block
constexpr int NBLK = (NE + EPB - 1) / EPB;   // 391
constexpr int MT = NN / 16;        // 3125 M-tiles (exact)
constexpr int MMB = 500;           // matmul blocks: 2 blocks/CU
constexpr int MMWAVES = MMB * 4;
constexpr int CAP = 8192;          // LDS edge cache per bucket
constexpr int CH1 = (NN + 127) / 128;   // 391 gather1 chunks (128 nodes each)
constexpr int CH2 = (NN + 255) / 256;   // 196 gather2 chunks (256 nodes each)

// float -> bf16 round-to-nearest-even
__device__ __forceinline__ unsigned short f2bf(float f) {
    unsigned int u = __float_as_uint(f);
    u += 0x7FFFu + ((u >> 16) & 1u);
    return (unsigned short)(u >> 16);
}
// packed bf16 pair -> two floats (low ushort = even element)
__device__ __forceinline__ float2 bf2f(unsigned int u) {
    return make_float2(__uint_as_float(u << 16), __uint_as_float(u & 0xFFFF0000u));
}
__device__ __forceinline__ bf16x8 pack8(float4 a, float4 b) {
    bf16x8 r;
    r[0] = (short)f2bf(a.x); r[1] = (short)f2bf(a.y);
    r[2] = (short)f2bf(a.z); r[3] = (short)f2bf(a.w);
    r[4] = (short)f2bf(b.x); r[5] = (short)f2bf(b.y);
    r[6] = (short)f2bf(b.z); r[7] = (short)f2bf(b.w);
    return r;
}
// accumulate 8 packed bf16 (uint4) into 8 fp32
__device__ __forceinline__ void addrow(float* a, uint4 v) {
    float2 p;
    p = bf2f(v.x); a[0] += p.x; a[1] += p.y;
    p = bf2f(v.y); a[2] += p.x; a[3] += p.y;
    p = bf2f(v.z); a[4] += p.x; a[5] += p.y;
    p = bf2f(v.w); a[6] += p.x; a[7] += p.y;
}

// pick (slice, chunk) for this block: slice = the XCD we are actually running on,
// chunk from that slice's atomic queue; spill to other slices if exhausted.
// Correct under ANY block->XCD mapping (total capacity == total blocks).
template <int CHUNKS>
__device__ __forceinline__ void pick_work(int* qc, int* sh2) {
    if (threadIdx.x == 0) {
        unsigned xcc;
        asm volatile("s_getreg_b32 %0, hwreg(HW_REG_XCC_ID)" : "=s"(xcc));
        int sl = (int)(xcc & 7u), ch = -1;
        #pragma unroll
        for (int a = 0; a < 8; a++) {
            int s2 = (sl + a) & 7;
            int c = atomicAdd(&qc[s2], 1);
            if (c < CHUNKS) { sl = s2; ch = c; break; }
        }
        sh2[0] = sl; sh2[1] = ch;
    }
    __syncthreads();
}

// ---------------- CSR build pass 1: per-block counting sort by coarse bucket ----------------
__global__ __launch_bounds__(256) void bin_kernel(const int* __restrict__ src,
                                                  const int* __restrict__ dst,
                                                  unsigned int* __restrict__ ebuf,
                                                  int* __restrict__ localOff,
                                                  int* __restrict__ qc) {
    __shared__ int lhist[NBK];
    __shared__ int ls[256];
    __shared__ int lcur[NBK];
    __shared__ unsigned int lbuf[EPB];
    const int t = threadIdx.x;
    const int base = blockIdx.x * EPB;
    if (blockIdx.x == 0 && t < 16) qc[t] = 0;   // zero gather work queues
    if (t < NBK) lhist[t] = 0;
    __syncthreads();
    int b[8]; unsigned int p[8];
    #pragma unroll
    for (int i = 0; i < 8; i++) {
        int e = base + i * 256 + t;
        if (e < NE) {
            int s = src[e], d = dst[e];
            b[i] = d >> 8;
            p[i] = ((unsigned int)(d & 255) << 16) | (unsigned int)s;
            atomicAdd(&lhist[b[i]], 1);
        } else b[i] = -1;
    }
    __syncthreads();
    int v = (t < NBK) ? lhist[t] : 0;
    ls[t] = v;
    __syncthreads();
    #pragma unroll
    for (int d = 1; d < 256; d <<= 1) {
        int u = (t >= d) ? ls[t - d] : 0;
        __syncthreads();
        ls[t] += u;
        __syncthreads();
    }
    if (t < NBK) {
        lcur[t] = ls[t] - v;
        localOff[blockIdx.x * 200 + t] = ls[t] - v;
    }
    if (t == NBK - 1) localOff[blockIdx.x * 200 + NBK] = ls[t];
    __syncthreads();
    #pragma unroll
    for (int i = 0; i < 8; i++) {
        if (b[i] >= 0) {
            int lp = atomicAdd(&lcur[b[i]], 1);
            lbuf[lp] = p[i];
        }
    }
    __syncthreads();
    #pragma unroll
    for (int i = 0; i < 8; i++)
        ebuf[base + i * 256 + t] = lbuf[i * 256 + t];   // tail garbage never read
}

// ---------------- CSR build pass 2: one block per bucket, bucket edges cached in LDS ---------
__global__ __launch_bounds__(256) void place_kernel(const unsigned int* __restrict__ ebuf,
                                                    const int* __restrict__ localOff,
                                                    unsigned short* __restrict__ esrc,
                                                    int* __restrict__ cnt,
                                                    int* __restrict__ off,
                                                    float* __restrict__ dinv) {
    __shared__ unsigned int lbuf[CAP];   // 32 KB
    __shared__ int lhist[256];
    __shared__ int ls[256];
    __shared__ int lcur[256];
    __shared__ int red[256];
    const int t = threadIdx.x;
    const int bkt = blockIdx.x;
    const int node0 = bkt << 8;
    const int nnodes = min(256, NN - node0);

    const int j0 = 2 * t, j1 = 2 * t + 1;
    int s0 = 0, l0 = 0, s1 = 0, l1 = 0;
    if (j0 < NBLK) { s0 = localOff[j0 * 200 + bkt]; l0 = localOff[j0 * 200 + bkt + 1] - s0; }
    if (j1 < NBLK) { s1 = localOff[j1 * 200 + bkt]; l1 = localOff[j1 * 200 + bkt + 1] - s1; }

    red[t] = s0 + s1;          // -> segBase (sum of chunk-local exclusive prefixes)
    ls[t] = l0 + l1;           // -> lbuf base scan
    lhist[t] = 0;
    __syncthreads();
    #pragma unroll
    for (int d = 1; d < 256; d <<= 1) {
        int u = (t >= d) ? ls[t - d] : 0;
        int r = (t + d < 256) ? red[t + d] : 0;
        __syncthreads();
        ls[t] += u;
        red[t] += r;
        __syncthreads();
    }
    const int segBase = red[0];
    const int total = ls[255];
    const int base0 = ls[t] - (l0 + l1);
    const int base1 = base0 + l0;
    const bool fits = (total <= CAP);

    if (fits) {
        const unsigned int* q0 = ebuf + j0 * EPB + s0;
        for (int k = 0; k < l0; k++) lbuf[base0 + k] = q0[k];
        const unsigned int* q1 = ebuf + j1 * EPB + s1;
        for (int k = 0; k < l1; k++) lbuf[base1 + k] = q1[k];
        __syncthreads();
        for (int k = t; k < total; k += 256) atomicAdd(&lhist[lbuf[k] >> 16], 1);
    } else {
        const unsigned int* q0 = ebuf + j0 * EPB + s0;
        for (int k = 0; k < l0; k++) atomicAdd(&lhist[q0[k] >> 16], 1);
        const unsigned int* q1 = ebuf + j1 * EPB + s1;
        for (int k = 0; k < l1; k++) atomicAdd(&lhist[q1[k] >> 16], 1);
    }
    __syncthreads();
    int v = lhist[t];
    ls[t] = v;
    __syncthreads();
    #pragma unroll
    for (int d = 1; d < 256; d <<= 1) {
        int u = (t >= d) ? ls[t - d] : 0;
        __syncthreads();
        ls[t] += u;
        __syncthreads();
    }
    int ex = ls[t] - v;
    lcur[t] = ex;
    if (t < nnodes) {
        cnt[node0 + t] = v;
        off[node0 + t] = segBase + ex;
        dinv[node0 + t] = rsqrtf((float)v + 1.0f);
    }
    __syncthreads();
    if (fits) {
        for (int k = t; k < total; k += 256) {
            unsigned int pp = lbuf[k];
            int lp = atomicAdd(&lcur[pp >> 16], 1);
            esrc[segBase + lp] = (unsigned short)(pp & 0xFFFFu);
        }
    } else {
        const unsigned int* q0 = ebuf + j0 * EPB + s0;
        for (int k = 0; k < l0; k++) {
            unsigned int pp = q0[k];
            int lp = atomicAdd(&lcur[pp >> 16], 1);
            esrc[segBase + lp] = (unsigned short)(pp & 0xFFFFu);
        }
        const unsigned int* q1 = ebuf + j1 * EPB + s1;
        for (int k = 0; k < l1; k++) {
            unsigned int pp = q1[k];
            int lp = atomicAdd(&lcur[pp >> 16], 1);
            esrc[segBase + lp] = (unsigned short)(pp & 0xFFFFu);
        }
    }
}

// ---------------- mm1: g1 SLICE-MAJOR bf16 = dinv * (x @ W1) via MFMA 16x16x32 bf16 ----------
// g1 layout: [slice=8][node=NN][16ch] -- slice = nt (channel block of 16), contiguous 1.6 MB.
__global__ __launch_bounds__(256, 2) void mm1_kernel(const float* __restrict__ x,
                                                     const float* __restrict__ W,
                                                     const float* __restrict__ dinv,
                                                     unsigned short* __restrict__ g1) {
    __shared__ unsigned short wl[4][8][64][8];   // 32 KB, B-fragment order
    const int t = threadIdx.x;
    for (int i = 0; i < 64; i++) {
        int idx = i * 256 + t;
        int k = idx >> 7, n = idx & 127;
        wl[k >> 5][n >> 4][((k >> 3) & 3) * 16 + (n & 15)][k & 7] = f2bf(W[idx]);
    }
    __syncthreads();
    const int lane = t & 63, lm = lane & 15, quad = lane >> 4;

    bf16x8 bfr[4][8];
    #pragma unroll
    for (int s = 0; s < 4; s++)
        #pragma unroll
        for (int nt = 0; nt < 8; nt++)
            bfr[s][nt] = *(const bf16x8*)&wl[s][nt][lane][0];

    int wg = blockIdx.x * 4 + (t >> 6);
    for (int tile = wg; tile < MT; tile += MMWAVES) {
        int row0 = tile << 4;
        const float* xr = x + (size_t)(row0 + lm) * 128 + quad * 8;
        bf16x8 af[4];
        #pragma unroll
        for (int s = 0; s < 4; s++) {
            float4 p = *(const float4*)(xr + s * 32);
            float4 q = *(const float4*)(xr + s * 32 + 4);
            af[s] = pack8(p, q);
        }
        f32x4 acc[8];
        #pragma unroll
        for (int nt = 0; nt < 8; nt++) acc[nt] = (f32x4){0.f, 0.f, 0.f, 0.f};
        #pragma unroll
        for (int s = 0; s < 4; s++)
            #pragma unroll
            for (int nt = 0; nt < 8; nt++)
                acc[nt] = __builtin_amdgcn_mfma_f32_16x16x32_bf16(af[s], bfr[s][nt],
                                                                  acc[nt], 0, 0, 0);
        float4 dv = *(const float4*)(dinv + row0 + quad * 4);
        float dvv[4] = {dv.x, dv.y, dv.z, dv.w};
        #pragma unroll
        for (int nt = 0; nt < 8; nt++)
            #pragma unroll
            for (int r = 0; r < 4; r++)
                g1[(size_t)nt * (NN * 16) + (size_t)(row0 + quad * 4 + r) * 16 + lm] =
                    f2bf(acc[nt][r] * dvv[r]);
    }
}

// ---------------- mm2: g2 SLICE-MAJOR bf16 = dinv * (x2 @ W2) -------------------------------
// g2 layout: [slice=8][node=NN][8ch] -- slice = nt*2 + (lm>>3).
__global__ __launch_bounds__(256, 2) void mm2_kernel(const unsigned short* __restrict__ x2,
                                                     const float* __restrict__ W,
                                                     const float* __restrict__ dinv,
                                                     unsigned short* __restrict__ g2) {
    __shared__ unsigned short wl[4][4][64][8];   // 16 KB
    const int t = threadIdx.x;
    for (int i = 0; i < 32; i++) {
        int idx = i * 256 + t;
        int k = idx >> 6, n = idx & 63;
        wl[k >> 5][n >> 4][((k >> 3) & 3) * 16 + (n & 15)][k & 7] = f2bf(W[idx]);
    }
    __syncthreads();
    const int lane = t & 63, lm = lane & 15, quad = lane >> 4;

    bf16x8 bfr[4][4];
    #pragma unroll
    for (int s = 0; s < 4; s++)
        #pragma unroll
        for (int nt = 0; nt < 4; nt++)
            bfr[s][nt] = *(const bf16x8*)&wl[s][nt][lane][0];

    int wg = blockIdx.x * 4 + (t >> 6);
    for (int tile = wg; tile < MT; tile += MMWAVES) {
        int row0 = tile << 4;
        const bf16x8* xr = (const bf16x8*)(x2 + (size_t)(row0 + lm) * 128 + quad * 8);
        bf16x8 af[4];
        #pragma unroll
        for (int s = 0; s < 4; s++) af[s] = xr[s * 4];
        f32x4 acc[4];
        #pragma unroll
        for (int nt = 0; nt < 4; nt++) acc[nt] = (f32x4){0.f, 0.f, 0.f, 0.f};
        #pragma unroll
        for (int s = 0; s < 4; s++)
            #pragma unroll
            for (int nt = 0; nt < 4; nt++)
                acc[nt] = __builtin_amdgcn_mfma_f32_16x16x32_bf16(af[s], bfr[s][nt],
                                                                  acc[nt], 0, 0, 0);
        float4 dv = *(const float4*)(dinv + row0 + quad * 4);
        float dvv[4] = {dv.x, dv.y, dv.z, dv.w};
        #pragma unroll
        for (int nt = 0; nt < 4; nt++)
            #pragma unroll
            for (int r = 0; r < 4; r++)
                g2[(size_t)(nt * 2 + (lm >> 3)) * (NN * 8) +
                   (size_t)(row0 + quad * 4 + r) * 8 + (lm & 7)] =
                    f2bf(acc[nt][r] * dvv[r]);
    }
}

// ---------------- gather1: XCC_ID-pinned slice-major gather ---------------------------------
// Slice = 16 ch = 32 B granule, contiguous 1.6 MB per slice -> lives in ONE XCD's L2.
// Block picks slice == its actual XCD (s_getreg XCC_ID) + node-chunk from atomic queue.
// Group = 2 lanes x uint4; block covers 128 nodes.
__global__ __launch_bounds__(256) void gather1_kernel(const unsigned short* __restrict__ g1,
                                                      const unsigned short* __restrict__ esrc,
                                                      const int* __restrict__ off,
                                                      const int* __restrict__ cnt,
                                                      const float* __restrict__ dinv,
                                                      const float* __restrict__ b1,
                                                      unsigned short* __restrict__ x2,
                                                      int* __restrict__ qc) {
    __shared__ int sh2[2];
    pick_work<CH1>(qc, sh2);
    const int slice = sh2[0], chunk = sh2[1];
    if (chunk < 0) return;
    const int n = chunk * 128 + (threadIdx.x >> 1);
    if (n >= NN) return;
    const int p = threadIdx.x & 1;
    const uint4* G = (const uint4*)(g1 + (size_t)slice * (NN * 16));   // node stride 2 uint4
    float a0[8] = {0,0,0,0,0,0,0,0};
    float a1[8] = {0,0,0,0,0,0,0,0};
    addrow(a0, G[(size_t)n * 2 + p]);            // self-loop (rows pre-scaled by dinv[src])
    int s0 = off[n], c = cnt[n];
    int i = 0;
    for (; i + 1 < c; i += 2) {
        int sA = esrc[s0 + i];
        int sB = esrc[s0 + i + 1];
        uint4 vA = G[(size_t)sA * 2 + p];
        uint4 vB = G[(size_t)sB * 2 + p];
        addrow(a0, vA);
        addrow(a1, vB);
    }
    if (i < c) addrow(a0, G[(size_t)esrc[s0 + i] * 2 + p]);
    #pragma unroll
    for (int j = 0; j < 8; j++) a0[j] += a1[j];
    float sc = dinv[n];
    const int ch0 = slice * 16 + p * 8;
    float4 bA = *(const float4*)(b1 + ch0);
    float4 bB = *(const float4*)(b1 + ch0 + 4);
    float4 pp = make_float4(fmaxf(sc * a0[0] + bA.x, 0.f), fmaxf(sc * a0[1] + bA.y, 0.f),
                            fmaxf(sc * a0[2] + bA.z, 0.f), fmaxf(sc * a0[3] + bA.w, 0.f));
    float4 qq = make_float4(fmaxf(sc * a0[4] + bB.x, 0.f), fmaxf(sc * a0[5] + bB.y, 0.f),
                            fmaxf(sc * a0[6] + bB.z, 0.f), fmaxf(sc * a0[7] + bB.w, 0.f));
    bf16x8 vout = pack8(pp, qq);
    __builtin_nontemporal_store(vout, (bf16x8*)(x2 + (size_t)n * 128 + ch0));
}

// ---------------- gather2: XCC_ID-pinned slice-major, 8 ch/slice (16 B granule, 1 lane/node) -
__global__ __launch_bounds__(256) void gather2_kernel(const unsigned short* __restrict__ g2,
                                                      const unsigned short* __restrict__ esrc,
                                                      const int* __restrict__ off,
                                                      const int* __restrict__ cnt,
                                                      const float* __restrict__ dinv,
                                                      const float* __restrict__ b2,
                                                      float* __restrict__ out,
                                                      int* __restrict__ qc) {
    __shared__ int sh2[2];
    pick_work<CH2>(qc, sh2);
    const int slice = sh2[0], chunk = sh2[1];
    if (chunk < 0) return;
    const int n = chunk * 256 + threadIdx.x;
    if (n >= NN) return;
    const uint4* G = (const uint4*)(g2 + (size_t)slice * (NN * 8));    // node stride 1 uint4
    float a0[8] = {0,0,0,0,0,0,0,0};
    float a1[8] = {0,0,0,0,0,0,0,0};
    addrow(a0, G[n]);                            // self-loop
    int s0 = off[n], c = cnt[n];
    int i = 0;
    for (; i + 1 < c; i += 2) {
        int sA = esrc[s0 + i];
        int sB = esrc[s0 + i + 1];
        uint4 vA = G[sA];
        uint4 vB = G[sB];
        addrow(a0, vA);
        addrow(a1, vB);
    }
    if (i < c) addrow(a0, G[esrc[s0 + i]]);
    #pragma unroll
    for (int j = 0; j < 8; j++) a0[j] += a1[j];
    float sc = dinv[n];
    const int ch0 = slice * 8;
    float4 bA = *(const float4*)(b2 + ch0);
    float4 bB = *(const float4*)(b2 + ch0 + 4);
    float* o = out + (size_t)n * 64 + ch0;
    f32x4 o0 = {sc * a0[0] + bA.x, sc * a0[1] + bA.y,
                sc * a0[2] + bA.z, sc * a0[3] + bA.w};
    f32x4 o1 = {sc * a0[4] + bB.x, sc * a0[5] + bB.y,
                sc * a0[6] + bB.z, sc * a0[7] + bB.w};
    __builtin_nontemporal_store(o0, (f32x4*)o);
    __builtin_nontemporal_store(o1, (f32x4*)(o + 4));
}

extern "C" void kernel_launch(void* const* d_in, const int* in_sizes, int n_in,
                              void* d_out, int out_size, void* d_ws, size_t ws_size,
                              hipStream_t stream) {
    const float* x  = (const float*)d_in[0];
    const int* edges = (const int*)d_in[1];     // [2, NE] int32
    const float* W1 = (const float*)d_in[2];
    const float* b1 = (const float*)d_in[3];
    const float* W2 = (const float*)d_in[4];
    const float* b2 = (const float*)d_in[5];
    const int* src = edges;
    const int* dst = edges + NE;

    // workspace layout (all chunks 16B-aligned)
    int* localOff  = (int*)d_ws;                        // NBLK*200 = 78200, pad 78208
    unsigned int* ebuf = (unsigned int*)(localOff + 78208);   // NBLK*EPB = 800768
    unsigned short* esrc = (unsigned short*)(ebuf + (size_t)NBLK * EPB);  // 800000 u16, pad 800768
    int* cnt       = (int*)(esrc + 800768);             // 50048
    int* off       = cnt + 50048;                       // 50048
    float* dinv    = (float*)(off + 50048);             // 50048
    int* qc        = (int*)(dinv + 50048);              // 16 (qc1 = qc, qc2 = qc+8)
    unsigned short* g1 = (unsigned short*)(qc + 16);    // [8][NN][16] bf16 slice-major
    unsigned short* x2 = g1 + (size_t)NN * C1;          // [N][128] bf16 row-major
    unsigned short* g2 = g1;                            // alias: g1 dead before mm2
    float* out = (float*)d_out;

    bin_kernel<<<NBLK, 256, 0, stream>>>(src, dst, ebuf, localOff, qc);
    place_kernel<<<NBK, 256, 0, stream>>>(ebuf, localOff, esrc, cnt, off, dinv);

    mm1_kernel<<<MMB, 256, 0, stream>>>(x, W1, dinv, g1);
    gather1_kernel<<<8 * CH1, 256, 0, stream>>>(g1, esrc, off, cnt, dinv, b1, x2, qc);

    mm2_kernel<<<MMB, 256, 0, stream>>>(x2, W2, dinv, g2);
    gather2_kernel<<<8 * CH2, 256, 0, stream>>>(g2, esrc, off, cnt, dinv, b2, out, qc + 8);
}

// Round 4
// 211.458 us; speedup vs baseline: 1.2177x; 1.2177x over previous
//
#include <hip/hip_runtime.h>

typedef __attribute__((ext_vector_type(8))) short bf16x8;
typedef __attribute__((ext_vector_type(4))) float f32x4;

constexpr int NN = 50000;          // nodes
constexpr int NE = 800000;         // edges
constexpr int C1 = 128;            // in/hidden channels
constexpr int C2 = 64;             // out channels
constexpr int NBK = 196;           // dst buckets of 256 nodes
constexpr int EPB = 2048;          // edges per bin block
constexpr int NBLK = (NE + EPB - 1) / EPB;   // 391
constexpr int MT = NN / 16;        // 3125 M-tiles (exact)
constexpr int MMB = 500;           // matmul blocks: 2 blocks/CU
constexpr int MMWAVES = MMB * 4;
constexpr int CAP = 8192;          // LDS edge cache per bucket
constexpr int CHN = (NN + 63) / 64;   // 782 gather chunks (64 nodes each)

// float -> bf16 round-to-nearest-even
__device__ __forceinline__ unsigned short f2bf(float f) {
    unsigned int u = __float_as_uint(f);
    u += 0x7FFFu + ((u >> 16) & 1u);
    return (unsigned short)(u >> 16);
}
// packed bf16 pair -> two floats (low ushort = even element)
__device__ __forceinline__ float2 bf2f(unsigned int u) {
    return make_float2(__uint_as_float(u << 16), __uint_as_float(u & 0xFFFF0000u));
}
__device__ __forceinline__ bf16x8 pack8(float4 a, float4 b) {
    bf16x8 r;
    r[0] = (short)f2bf(a.x); r[1] = (short)f2bf(a.y);
    r[2] = (short)f2bf(a.z); r[3] = (short)f2bf(a.w);
    r[4] = (short)f2bf(b.x); r[5] = (short)f2bf(b.y);
    r[6] = (short)f2bf(b.z); r[7] = (short)f2bf(b.w);
    return r;
}
// accumulate 8 packed bf16 (uint4) into 8 fp32
__device__ __forceinline__ void addrow(float* a, uint4 v) {
    float2 p;
    p = bf2f(v.x); a[0] += p.x; a[1] += p.y;
    p = bf2f(v.y); a[2] += p.x; a[3] += p.y;
    p = bf2f(v.z); a[4] += p.x; a[5] += p.y;
    p = bf2f(v.w); a[6] += p.x; a[7] += p.y;
}

// pick (slice, chunk): slice = the XCD we actually run on (mod NSLICE), chunk from that
// slice's atomic queue; spill to other slices if exhausted. Correct under ANY block->XCD
// mapping: capacity == grid size and each block claims <=1, so the scan always succeeds.
template <int NSLICE, int CHUNKS>
__device__ __forceinline__ void pick_work(int* qc, int* sh2) {
    if (threadIdx.x == 0) {
        unsigned xcc;
        asm volatile("s_getreg_b32 %0, hwreg(HW_REG_XCC_ID)" : "=s"(xcc));
        int sl = (int)(xcc & (NSLICE - 1)), ch = -1;
        #pragma unroll
        for (int a = 0; a < NSLICE; a++) {
            int s2 = (sl + a) & (NSLICE - 1);
            int c = atomicAdd(&qc[s2], 1);
            if (c < CHUNKS) { sl = s2; ch = c; break; }
        }
        sh2[0] = sl; sh2[1] = ch;
    }
    __syncthreads();
}

// ---------------- CSR build pass 1: per-block counting sort by coarse bucket ----------------
__global__ __launch_bounds__(256) void bin_kernel(const int* __restrict__ src,
                                                  const int* __restrict__ dst,
                                                  unsigned int* __restrict__ ebuf,
                                                  int* __restrict__ localOff,
                                                  int* __restrict__ qc) {
    __shared__ int lhist[NBK];
    __shared__ int ls[256];
    __shared__ int lcur[NBK];
    __shared__ unsigned int lbuf[EPB];
    const int t = threadIdx.x;
    const int base = blockIdx.x * EPB;
    if (blockIdx.x == 0 && t < 16) qc[t] = 0;   // zero gather work queues
    if (t < NBK) lhist[t] = 0;
    __syncthreads();
    int b[8]; unsigned int p[8];
    #pragma unroll
    for (int i = 0; i < 8; i++) {
        int e = base + i * 256 + t;
        if (e < NE) {
            int s = src[e], d = dst[e];
            b[i] = d >> 8;
            p[i] = ((unsigned int)(d & 255) << 16) | (unsigned int)s;
            atomicAdd(&lhist[b[i]], 1);
        } else b[i] = -1;
    }
    __syncthreads();
    int v = (t < NBK) ? lhist[t] : 0;
    ls[t] = v;
    __syncthreads();
    #pragma unroll
    for (int d = 1; d < 256; d <<= 1) {
        int u = (t >= d) ? ls[t - d] : 0;
        __syncthreads();
        ls[t] += u;
        __syncthreads();
    }
    if (t < NBK) {
        lcur[t] = ls[t] - v;
        localOff[blockIdx.x * 200 + t] = ls[t] - v;
    }
    if (t == NBK - 1) localOff[blockIdx.x * 200 + NBK] = ls[t];
    __syncthreads();
    #pragma unroll
    for (int i = 0; i < 8; i++) {
        if (b[i] >= 0) {
            int lp = atomicAdd(&lcur[b[i]], 1);
            lbuf[lp] = p[i];
        }
    }
    __syncthreads();
    #pragma unroll
    for (int i = 0; i < 8; i++)
        ebuf[base + i * 256 + t] = lbuf[i * 256 + t];   // tail garbage never read
}

// ---------------- CSR build pass 2: one block per bucket, bucket edges cached in LDS ---------
__global__ __launch_bounds__(256) void place_kernel(const unsigned int* __restrict__ ebuf,
                                                    const int* __restrict__ localOff,
                                                    unsigned short* __restrict__ esrc,
                                                    int* __restrict__ cnt,
                                                    int* __restrict__ off,
                                                    float* __restrict__ dinv) {
    __shared__ unsigned int lbuf[CAP];   // 32 KB
    __shared__ int lhist[256];
    __shared__ int ls[256];
    __shared__ int lcur[256];
    __shared__ int red[256];
    const int t = threadIdx.x;
    const int bkt = blockIdx.x;
    const int node0 = bkt << 8;
    const int nnodes = min(256, NN - node0);

    const int j0 = 2 * t, j1 = 2 * t + 1;
    int s0 = 0, l0 = 0, s1 = 0, l1 = 0;
    if (j0 < NBLK) { s0 = localOff[j0 * 200 + bkt]; l0 = localOff[j0 * 200 + bkt + 1] - s0; }
    if (j1 < NBLK) { s1 = localOff[j1 * 200 + bkt]; l1 = localOff[j1 * 200 + bkt + 1] - s1; }

    red[t] = s0 + s1;          // -> segBase (sum of chunk-local exclusive prefixes)
    ls[t] = l0 + l1;           // -> lbuf base scan
    lhist[t] = 0;
    __syncthreads();
    #pragma unroll
    for (int d = 1; d < 256; d <<= 1) {
        int u = (t >= d) ? ls[t - d] : 0;
        int r = (t + d < 256) ? red[t + d] : 0;
        __syncthreads();
        ls[t] += u;
        red[t] += r;
        __syncthreads();
    }
    const int segBase = red[0];
    const int total = ls[255];
    const int base0 = ls[t] - (l0 + l1);
    const int base1 = base0 + l0;
    const bool fits = (total <= CAP);

    if (fits) {
        const unsigned int* q0 = ebuf + j0 * EPB + s0;
        for (int k = 0; k < l0; k++) lbuf[base0 + k] = q0[k];
        const unsigned int* q1 = ebuf + j1 * EPB + s1;
        for (int k = 0; k < l1; k++) lbuf[base1 + k] = q1[k];
        __syncthreads();
        for (int k = t; k < total; k += 256) atomicAdd(&lhist[lbuf[k] >> 16], 1);
    } else {
        const unsigned int* q0 = ebuf + j0 * EPB + s0;
        for (int k = 0; k < l0; k++) atomicAdd(&lhist[q0[k] >> 16], 1);
        const unsigned int* q1 = ebuf + j1 * EPB + s1;
        for (int k = 0; k < l1; k++) atomicAdd(&lhist[q1[k] >> 16], 1);
    }
    __syncthreads();
    int v = lhist[t];
    ls[t] = v;
    __syncthreads();
    #pragma unroll
    for (int d = 1; d < 256; d <<= 1) {
        int u = (t >= d) ? ls[t - d] : 0;
        __syncthreads();
        ls[t] += u;
        __syncthreads();
    }
    int ex = ls[t] - v;
    lcur[t] = ex;
    if (t < nnodes) {
        cnt[node0 + t] = v;
        off[node0 + t] = segBase + ex;
        dinv[node0 + t] = rsqrtf((float)v + 1.0f);
    }
    __syncthreads();
    if (fits) {
        for (int k = t; k < total; k += 256) {
            unsigned int pp = lbuf[k];
            int lp = atomicAdd(&lcur[pp >> 16], 1);
            esrc[segBase + lp] = (unsigned short)(pp & 0xFFFFu);
        }
    } else {
        const unsigned int* q0 = ebuf + j0 * EPB + s0;
        for (int k = 0; k < l0; k++) {
            unsigned int pp = q0[k];
            int lp = atomicAdd(&lcur[pp >> 16], 1);
            esrc[segBase + lp] = (unsigned short)(pp & 0xFFFFu);
        }
        const unsigned int* q1 = ebuf + j1 * EPB + s1;
        for (int k = 0; k < l1; k++) {
            unsigned int pp = q1[k];
            int lp = atomicAdd(&lcur[pp >> 16], 1);
            esrc[segBase + lp] = (unsigned short)(pp & 0xFFFFu);
        }
    }
}

// ---------------- mm1: g1 SLICE-MAJOR bf16 = dinv * (x @ W1) via MFMA 16x16x32 bf16 ----------
// g1 layout: [slice=4][node=NN][32ch] -- slice = nt>>1, 64 B/node granule, 3.2 MB/slice.
__global__ __launch_bounds__(256, 2) void mm1_kernel(const float* __restrict__ x,
                                                     const float* __restrict__ W,
                                                     const float* __restrict__ dinv,
                                                     unsigned short* __restrict__ g1) {
    __shared__ unsigned short wl[4][8][64][8];   // 32 KB, B-fragment order
    const int t = threadIdx.x;
    for (int i = 0; i < 64; i++) {
        int idx = i * 256 + t;
        int k = idx >> 7, n = idx & 127;
        wl[k >> 5][n >> 4][((k >> 3) & 3) * 16 + (n & 15)][k & 7] = f2bf(W[idx]);
    }
    __syncthreads();
    const int lane = t & 63, lm = lane & 15, quad = lane >> 4;

    bf16x8 bfr[4][8];
    #pragma unroll
    for (int s = 0; s < 4; s++)
        #pragma unroll
        for (int nt = 0; nt < 8; nt++)
            bfr[s][nt] = *(const bf16x8*)&wl[s][nt][lane][0];

    int wg = blockIdx.x * 4 + (t >> 6);
    for (int tile = wg; tile < MT; tile += MMWAVES) {
        int row0 = tile << 4;
        const float* xr = x + (size_t)(row0 + lm) * 128 + quad * 8;
        bf16x8 af[4];
        #pragma unroll
        for (int s = 0; s < 4; s++) {
            float4 p = *(const float4*)(xr + s * 32);
            float4 q = *(const float4*)(xr + s * 32 + 4);
            af[s] = pack8(p, q);
        }
        f32x4 acc[8];
        #pragma unroll
        for (int nt = 0; nt < 8; nt++) acc[nt] = (f32x4){0.f, 0.f, 0.f, 0.f};
        #pragma unroll
        for (int s = 0; s < 4; s++)
            #pragma unroll
            for (int nt = 0; nt < 8; nt++)
                acc[nt] = __builtin_amdgcn_mfma_f32_16x16x32_bf16(af[s], bfr[s][nt],
                                                                  acc[nt], 0, 0, 0);
        float4 dv = *(const float4*)(dinv + row0 + quad * 4);
        float dvv[4] = {dv.x, dv.y, dv.z, dv.w};
        #pragma unroll
        for (int nt = 0; nt < 8; nt++)
            #pragma unroll
            for (int r = 0; r < 4; r++)
                g1[(size_t)(nt >> 1) * (NN * 32) +
                   (size_t)(row0 + quad * 4 + r) * 32 + (nt & 1) * 16 + lm] =
                    f2bf(acc[nt][r] * dvv[r]);
    }
}

// ---------------- mm2: g2 SLICE-MAJOR bf16 = dinv * (x2 @ W2) -------------------------------
// g2 layout: [slice=2][node=NN][32ch] -- slice = nt>>1, 64 B/node granule, 3.2 MB/slice.
__global__ __launch_bounds__(256, 2) void mm2_kernel(const unsigned short* __restrict__ x2,
                                                     const float* __restrict__ W,
                                                     const float* __restrict__ dinv,
                                                     unsigned short* __restrict__ g2) {
    __shared__ unsigned short wl[4][4][64][8];   // 16 KB
    const int t = threadIdx.x;
    for (int i = 0; i < 32; i++) {
        int idx = i * 256 + t;
        int k = idx >> 6, n = idx & 63;
        wl[k >> 5][n >> 4][((k >> 3) & 3) * 16 + (n & 15)][k & 7] = f2bf(W[idx]);
    }
    __syncthreads();
    const int lane = t & 63, lm = lane & 15, quad = lane >> 4;

    bf16x8 bfr[4][4];
    #pragma unroll
    for (int s = 0; s < 4; s++)
        #pragma unroll
        for (int nt = 0; nt < 4; nt++)
            bfr[s][nt] = *(const bf16x8*)&wl[s][nt][lane][0];

    int wg = blockIdx.x * 4 + (t >> 6);
    for (int tile = wg; tile < MT; tile += MMWAVES) {
        int row0 = tile << 4;
        const bf16x8* xr = (const bf16x8*)(x2 + (size_t)(row0 + lm) * 128 + quad * 8);
        bf16x8 af[4];
        #pragma unroll
        for (int s = 0; s < 4; s++) af[s] = xr[s * 4];
        f32x4 acc[4];
        #pragma unroll
        for (int nt = 0; nt < 4; nt++) acc[nt] = (f32x4){0.f, 0.f, 0.f, 0.f};
        #pragma unroll
        for (int s = 0; s < 4; s++)
            #pragma unroll
            for (int nt = 0; nt < 4; nt++)
                acc[nt] = __builtin_amdgcn_mfma_f32_16x16x32_bf16(af[s], bfr[s][nt],
                                                                  acc[nt], 0, 0, 0);
        float4 dv = *(const float4*)(dinv + row0 + quad * 4);
        float dvv[4] = {dv.x, dv.y, dv.z, dv.w};
        #pragma unroll
        for (int nt = 0; nt < 4; nt++)
            #pragma unroll
            for (int r = 0; r < 4; r++)
                g2[(size_t)(nt >> 1) * (NN * 32) +
                   (size_t)(row0 + quad * 4 + r) * 32 + (nt & 1) * 16 + lm] =
                    f2bf(acc[nt][r] * dvv[r]);
    }
}

// ---------------- gather1: XCC-pinned, 4 slices x 32ch (64 B granule), unroll 4 -------------
// 4-lane group owns (node, slice); 64 nodes/block; slice = XCC_ID&3 (2 XCDs share a slice,
// each caches its own 3.2 MB copy; L3 absorbs the duplicate HBM fetch).
__global__ __launch_bounds__(256) void gather1_kernel(const unsigned short* __restrict__ g1,
                                                      const unsigned short* __restrict__ esrc,
                                                      const int* __restrict__ off,
                                                      const int* __restrict__ cnt,
                                                      const float* __restrict__ dinv,
                                                      const float* __restrict__ b1,
                                                      unsigned short* __restrict__ x2,
                                                      int* __restrict__ qc) {
    __shared__ int sh2[2];
    pick_work<4, CHN>(qc, sh2);
    const int slice = sh2[0], chunk = sh2[1];
    if (chunk < 0) return;
    const int n = chunk * 64 + (threadIdx.x >> 2);
    if (n >= NN) return;
    const int p = threadIdx.x & 3;
    const uint4* G = (const uint4*)(g1 + (size_t)slice * (NN * 32));   // node stride 4 uint4
    float a0[8] = {0,0,0,0,0,0,0,0};
    float a1[8] = {0,0,0,0,0,0,0,0};
    addrow(a0, G[(size_t)n * 4 + p]);            // self-loop (rows pre-scaled by dinv[src])
    int s0 = off[n], c = cnt[n];
    int i = 0;
    for (; i + 3 < c; i += 4) {
        int sA = esrc[s0 + i];
        int sB = esrc[s0 + i + 1];
        int sC = esrc[s0 + i + 2];
        int sD = esrc[s0 + i + 3];
        uint4 vA = G[(size_t)sA * 4 + p];
        uint4 vB = G[(size_t)sB * 4 + p];
        uint4 vC = G[(size_t)sC * 4 + p];
        uint4 vD = G[(size_t)sD * 4 + p];
        addrow(a0, vA);
        addrow(a1, vB);
        addrow(a0, vC);
        addrow(a1, vD);
    }
    for (; i < c; i++) addrow(a0, G[(size_t)esrc[s0 + i] * 4 + p]);
    #pragma unroll
    for (int j = 0; j < 8; j++) a0[j] += a1[j];
    float sc = dinv[n];
    const int ch0 = slice * 32 + p * 8;
    float4 bA = *(const float4*)(b1 + ch0);
    float4 bB = *(const float4*)(b1 + ch0 + 4);
    float4 pp = make_float4(fmaxf(sc * a0[0] + bA.x, 0.f), fmaxf(sc * a0[1] + bA.y, 0.f),
                            fmaxf(sc * a0[2] + bA.z, 0.f), fmaxf(sc * a0[3] + bA.w, 0.f));
    float4 qq = make_float4(fmaxf(sc * a0[4] + bB.x, 0.f), fmaxf(sc * a0[5] + bB.y, 0.f),
                            fmaxf(sc * a0[6] + bB.z, 0.f), fmaxf(sc * a0[7] + bB.w, 0.f));
    bf16x8 vout = pack8(pp, qq);
    __builtin_nontemporal_store(vout, (bf16x8*)(x2 + (size_t)n * 128 + ch0));
}

// ---------------- gather2: XCC-pinned, 2 slices x 32ch (64 B granule), unroll 4, fp32 out ----
__global__ __launch_bounds__(256) void gather2_kernel(const unsigned short* __restrict__ g2,
                                                      const unsigned short* __restrict__ esrc,
                                                      const int* __restrict__ off,
                                                      const int* __restrict__ cnt,
                                                      const float* __restrict__ dinv,
                                                      const float* __restrict__ b2,
                                                      float* __restrict__ out,
                                                      int* __restrict__ qc) {
    __shared__ int sh2[2];
    pick_work<2, CHN>(qc, sh2);
    const int slice = sh2[0], chunk = sh2[1];
    if (chunk < 0) return;
    const int n = chunk * 64 + (threadIdx.x >> 2);
    if (n >= NN) return;
    const int p = threadIdx.x & 3;
    const uint4* G = (const uint4*)(g2 + (size_t)slice * (NN * 32));   // node stride 4 uint4
    float a0[8] = {0,0,0,0,0,0,0,0};
    float a1[8] = {0,0,0,0,0,0,0,0};
    addrow(a0, G[(size_t)n * 4 + p]);            // self-loop
    int s0 = off[n], c = cnt[n];
    int i = 0;
    for (; i + 3 < c; i += 4) {
        int sA = esrc[s0 + i];
        int sB = esrc[s0 + i + 1];
        int sC = esrc[s0 + i + 2];
        int sD = esrc[s0 + i + 3];
        uint4 vA = G[(size_t)sA * 4 + p];
        uint4 vB = G[(size_t)sB * 4 + p];
        uint4 vC = G[(size_t)sC * 4 + p];
        uint4 vD = G[(size_t)sD * 4 + p];
        addrow(a0, vA);
        addrow(a1, vB);
        addrow(a0, vC);
        addrow(a1, vD);
    }
    for (; i < c; i++) addrow(a0, G[(size_t)esrc[s0 + i] * 4 + p]);
    #pragma unroll
    for (int j = 0; j < 8; j++) a0[j] += a1[j];
    float sc = dinv[n];
    const int ch0 = slice * 32 + p * 8;
    float4 bA = *(const float4*)(b2 + ch0);
    float4 bB = *(const float4*)(b2 + ch0 + 4);
    float* o = out + (size_t)n * 64 + ch0;
    f32x4 o0 = {sc * a0[0] + bA.x, sc * a0[1] + bA.y,
                sc * a0[2] + bA.z, sc * a0[3] + bA.w};
    f32x4 o1 = {sc * a0[4] + bB.x, sc * a0[5] + bB.y,
                sc * a0[6] + bB.z, sc * a0[7] + bB.w};
    __builtin_nontemporal_store(o0, (f32x4*)o);
    __builtin_nontemporal_store(o1, (f32x4*)(o + 4));
}

extern "C" void kernel_launch(void* const* d_in, const int* in_sizes, int n_in,
                              void* d_out, int out_size, void* d_ws, size_t ws_size,
                              hipStream_t stream) {
    const float* x  = (const float*)d_in[0];
    const int* edges = (const int*)d_in[1];     // [2, NE] int32
    const float* W1 = (const float*)d_in[2];
    const float* b1 = (const float*)d_in[3];
    const float* W2 = (const float*)d_in[4];
    const float* b2 = (const float*)d_in[5];
    const int* src = edges;
    const int* dst = edges + NE;

    // workspace layout (all chunks 16B-aligned)
    int* localOff  = (int*)d_ws;                        // NBLK*200 = 78200, pad 78208
    unsigned int* ebuf = (unsigned int*)(localOff + 78208);   // NBLK*EPB = 800768
    unsigned short* esrc = (unsigned short*)(ebuf + (size_t)NBLK * EPB);  // 800000 u16, pad 800768
    int* cnt       = (int*)(esrc + 800768);             // 50048
    int* off       = cnt + 50048;                       // 50048
    float* dinv    = (float*)(off + 50048);             // 50048
    int* qc        = (int*)(dinv + 50048);              // 16 (qc1 = qc, qc2 = qc+8)
    unsigned short* g1 = (unsigned short*)(qc + 16);    // [4][NN][32] bf16 slice-major
    unsigned short* x2 = g1 + (size_t)NN * C1;          // [N][128] bf16 row-major
    unsigned short* g2 = g1;                            // alias: g1 dead before mm2
    float* out = (float*)d_out;

    bin_kernel<<<NBLK, 256, 0, stream>>>(src, dst, ebuf, localOff, qc);
    place_kernel<<<NBK, 256, 0, stream>>>(ebuf, localOff, esrc, cnt, off, dinv);

    mm1_kernel<<<MMB, 256, 0, stream>>>(x, W1, dinv, g1);
    gather1_kernel<<<4 * CHN, 256, 0, stream>>>(g1, esrc, off, cnt, dinv, b1, x2, qc);

    mm2_kernel<<<MMB, 256, 0, stream>>>(x2, W2, dinv, g2);
    gather2_kernel<<<2 * CHN, 256, 0, stream>>>(g2, esrc, off, cnt, dinv, b2, out, qc + 8);
}

// Round 5
// 182.811 us; speedup vs baseline: 1.4085x; 1.1567x over previous
//
#include <hip/hip_runtime.h>

typedef __attribute__((ext_vector_type(8))) short bf16x8;
typedef __attribute__((ext_vector_type(4))) float f32x4;

constexpr int NN = 50000;          // nodes
constexpr int NE = 800000;         // edges
constexpr int C1 = 128;            // in/hidden channels
constexpr int C2 = 64;             // out channels
constexpr int NBK = 196;           // dst buckets of 256 nodes
constexpr int EPB = 2048;          // edges per bin block
constexpr int NBLK = (NE + EPB - 1) / EPB;   // 391
constexpr int MT = NN / 16;        // 3125 M-tiles (exact)
constexpr int MMB = 500;           // matmul blocks: 2 blocks/CU
constexpr int MMWAVES = MMB * 4;
constexpr int CAP = 8192;          // LDS edge cache per bucket
constexpr int GB = (NN + 3) / 4;   // 12500 gather blocks (4 waves = 4 nodes each)

// float -> bf16 round-to-nearest-even
__device__ __forceinline__ unsigned short f2bf(float f) {
    unsigned int u = __float_as_uint(f);
    u += 0x7FFFu + ((u >> 16) & 1u);
    return (unsigned short)(u >> 16);
}
// packed bf16 pair -> two floats (low ushort = even element)
__device__ __forceinline__ float2 bf2f(unsigned int u) {
    return make_float2(__uint_as_float(u << 16), __uint_as_float(u & 0xFFFF0000u));
}
__device__ __forceinline__ bf16x8 pack8(float4 a, float4 b) {
    bf16x8 r;
    r[0] = (short)f2bf(a.x); r[1] = (short)f2bf(a.y);
    r[2] = (short)f2bf(a.z); r[3] = (short)f2bf(a.w);
    r[4] = (short)f2bf(b.x); r[5] = (short)f2bf(b.y);
    r[6] = (short)f2bf(b.z); r[7] = (short)f2bf(b.w);
    return r;
}

// ---------------- CSR build pass 1: per-block counting sort by coarse bucket ----------------
__global__ __launch_bounds__(256) void bin_kernel(const int* __restrict__ src,
                                                  const int* __restrict__ dst,
                                                  unsigned int* __restrict__ ebuf,
                                                  int* __restrict__ localOff) {
    __shared__ int lhist[NBK];
    __shared__ int ls[256];
    __shared__ int lcur[NBK];
    __shared__ unsigned int lbuf[EPB];
    const int t = threadIdx.x;
    const int base = blockIdx.x * EPB;
    if (t < NBK) lhist[t] = 0;
    __syncthreads();
    int b[8]; unsigned int p[8];
    #pragma unroll
    for (int i = 0; i < 8; i++) {
        int e = base + i * 256 + t;
        if (e < NE) {
            int s = src[e], d = dst[e];
            b[i] = d >> 8;
            p[i] = ((unsigned int)(d & 255) << 16) | (unsigned int)s;
            atomicAdd(&lhist[b[i]], 1);
        } else b[i] = -1;
    }
    __syncthreads();
    int v = (t < NBK) ? lhist[t] : 0;
    ls[t] = v;
    __syncthreads();
    #pragma unroll
    for (int d = 1; d < 256; d <<= 1) {
        int u = (t >= d) ? ls[t - d] : 0;
        __syncthreads();
        ls[t] += u;
        __syncthreads();
    }
    if (t < NBK) {
        lcur[t] = ls[t] - v;
        localOff[blockIdx.x * 200 + t] = ls[t] - v;
    }
    if (t == NBK - 1) localOff[blockIdx.x * 200 + NBK] = ls[t];
    __syncthreads();
    #pragma unroll
    for (int i = 0; i < 8; i++) {
        if (b[i] >= 0) {
            int lp = atomicAdd(&lcur[b[i]], 1);
            lbuf[lp] = p[i];
        }
    }
    __syncthreads();
    #pragma unroll
    for (int i = 0; i < 8; i++)
        ebuf[base + i * 256 + t] = lbuf[i * 256 + t];   // tail garbage never read
}

// ---------------- CSR build pass 2: one block per bucket, bucket edges cached in LDS ---------
__global__ __launch_bounds__(256) void place_kernel(const unsigned int* __restrict__ ebuf,
                                                    const int* __restrict__ localOff,
                                                    unsigned short* __restrict__ esrc,
                                                    int* __restrict__ cnt,
                                                    int* __restrict__ off,
                                                    float* __restrict__ dinv) {
    __shared__ unsigned int lbuf[CAP];   // 32 KB
    __shared__ int lhist[256];
    __shared__ int ls[256];
    __shared__ int lcur[256];
    __shared__ int red[256];
    const int t = threadIdx.x;
    const int bkt = blockIdx.x;
    const int node0 = bkt << 8;
    const int nnodes = min(256, NN - node0);

    const int j0 = 2 * t, j1 = 2 * t + 1;
    int s0 = 0, l0 = 0, s1 = 0, l1 = 0;
    if (j0 < NBLK) { s0 = localOff[j0 * 200 + bkt]; l0 = localOff[j0 * 200 + bkt + 1] - s0; }
    if (j1 < NBLK) { s1 = localOff[j1 * 200 + bkt]; l1 = localOff[j1 * 200 + bkt + 1] - s1; }

    red[t] = s0 + s1;          // -> segBase (sum of chunk-local exclusive prefixes)
    ls[t] = l0 + l1;           // -> lbuf base scan
    lhist[t] = 0;
    __syncthreads();
    #pragma unroll
    for (int d = 1; d < 256; d <<= 1) {
        int u = (t >= d) ? ls[t - d] : 0;
        int r = (t + d < 256) ? red[t + d] : 0;
        __syncthreads();
        ls[t] += u;
        red[t] += r;
        __syncthreads();
    }
    const int segBase = red[0];
    const int total = ls[255];
    const int base0 = ls[t] - (l0 + l1);
    const int base1 = base0 + l0;
    const bool fits = (total <= CAP);

    if (fits) {
        const unsigned int* q0 = ebuf + j0 * EPB + s0;
        for (int k = 0; k < l0; k++) lbuf[base0 + k] = q0[k];
        const unsigned int* q1 = ebuf + j1 * EPB + s1;
        for (int k = 0; k < l1; k++) lbuf[base1 + k] = q1[k];
        __syncthreads();
        for (int k = t; k < total; k += 256) atomicAdd(&lhist[lbuf[k] >> 16], 1);
    } else {
        const unsigned int* q0 = ebuf + j0 * EPB + s0;
        for (int k = 0; k < l0; k++) atomicAdd(&lhist[q0[k] >> 16], 1);
        const unsigned int* q1 = ebuf + j1 * EPB + s1;
        for (int k = 0; k < l1; k++) atomicAdd(&lhist[q1[k] >> 16], 1);
    }
    __syncthreads();
    int v = lhist[t];
    ls[t] = v;
    __syncthreads();
    #pragma unroll
    for (int d = 1; d < 256; d <<= 1) {
        int u = (t >= d) ? ls[t - d] : 0;
        __syncthreads();
        ls[t] += u;
        __syncthreads();
    }
    int ex = ls[t] - v;
    lcur[t] = ex;
    if (t < nnodes) {
        cnt[node0 + t] = v;
        off[node0 + t] = segBase + ex;
        dinv[node0 + t] = rsqrtf((float)v + 1.0f);
    }
    __syncthreads();
    if (fits) {
        for (int k = t; k < total; k += 256) {
            unsigned int pp = lbuf[k];
            int lp = atomicAdd(&lcur[pp >> 16], 1);
            esrc[segBase + lp] = (unsigned short)(pp & 0xFFFFu);
        }
    } else {
        const unsigned int* q0 = ebuf + j0 * EPB + s0;
        for (int k = 0; k < l0; k++) {
            unsigned int pp = q0[k];
            int lp = atomicAdd(&lcur[pp >> 16], 1);
            esrc[segBase + lp] = (unsigned short)(pp & 0xFFFFu);
        }
        const unsigned int* q1 = ebuf + j1 * EPB + s1;
        for (int k = 0; k < l1; k++) {
            unsigned int pp = q1[k];
            int lp = atomicAdd(&lcur[pp >> 16], 1);
            esrc[segBase + lp] = (unsigned short)(pp & 0xFFFFu);
        }
    }
}

// ---------------- mm1: g1(bf16, row-major) = dinv * (x @ W1) via MFMA 16x16x32 bf16 ----------
__global__ __launch_bounds__(256, 2) void mm1_kernel(const float* __restrict__ x,
                                                     const float* __restrict__ W,
                                                     const float* __restrict__ dinv,
                                                     unsigned short* __restrict__ g1) {
    __shared__ unsigned short wl[4][8][64][8];   // 32 KB, B-fragment order
    const int t = threadIdx.x;
    for (int i = 0; i < 64; i++) {
        int idx = i * 256 + t;
        int k = idx >> 7, n = idx & 127;
        wl[k >> 5][n >> 4][((k >> 3) & 3) * 16 + (n & 15)][k & 7] = f2bf(W[idx]);
    }
    __syncthreads();
    const int lane = t & 63, lm = lane & 15, quad = lane >> 4;

    bf16x8 bfr[4][8];
    #pragma unroll
    for (int s = 0; s < 4; s++)
        #pragma unroll
        for (int nt = 0; nt < 8; nt++)
            bfr[s][nt] = *(const bf16x8*)&wl[s][nt][lane][0];

    int wg = blockIdx.x * 4 + (t >> 6);
    for (int tile = wg; tile < MT; tile += MMWAVES) {
        int row0 = tile << 4;
        const float* xr = x + (size_t)(row0 + lm) * 128 + quad * 8;
        bf16x8 af[4];
        #pragma unroll
        for (int s = 0; s < 4; s++) {
            float4 p = *(const float4*)(xr + s * 32);
            float4 q = *(const float4*)(xr + s * 32 + 4);
            af[s] = pack8(p, q);
        }
        f32x4 acc[8];
        #pragma unroll
        for (int nt = 0; nt < 8; nt++) acc[nt] = (f32x4){0.f, 0.f, 0.f, 0.f};
        #pragma unroll
        for (int s = 0; s < 4; s++)
            #pragma unroll
            for (int nt = 0; nt < 8; nt++)
                acc[nt] = __builtin_amdgcn_mfma_f32_16x16x32_bf16(af[s], bfr[s][nt],
                                                                  acc[nt], 0, 0, 0);
        float4 dv = *(const float4*)(dinv + row0 + quad * 4);
        float dvv[4] = {dv.x, dv.y, dv.z, dv.w};
        #pragma unroll
        for (int nt = 0; nt < 8; nt++)
            #pragma unroll
            for (int r = 0; r < 4; r++)
                g1[(size_t)(row0 + quad * 4 + r) * 128 + nt * 16 + lm] =
                    f2bf(acc[nt][r] * dvv[r]);
    }
}

// ---------------- mm2: g2(bf16, row-major) = dinv * (x2 @ W2), x2 already bf16 ---------------
__global__ __launch_bounds__(256, 2) void mm2_kernel(const unsigned short* __restrict__ x2,
                                                     const float* __restrict__ W,
                                                     const float* __restrict__ dinv,
                                                     unsigned short* __restrict__ g2) {
    __shared__ unsigned short wl[4][4][64][8];   // 16 KB
    const int t = threadIdx.x;
    for (int i = 0; i < 32; i++) {
        int idx = i * 256 + t;
        int k = idx >> 6, n = idx & 63;
        wl[k >> 5][n >> 4][((k >> 3) & 3) * 16 + (n & 15)][k & 7] = f2bf(W[idx]);
    }
    __syncthreads();
    const int lane = t & 63, lm = lane & 15, quad = lane >> 4;

    bf16x8 bfr[4][4];
    #pragma unroll
    for (int s = 0; s < 4; s++)
        #pragma unroll
        for (int nt = 0; nt < 4; nt++)
            bfr[s][nt] = *(const bf16x8*)&wl[s][nt][lane][0];

    int wg = blockIdx.x * 4 + (t >> 6);
    for (int tile = wg; tile < MT; tile += MMWAVES) {
        int row0 = tile << 4;
        const bf16x8* xr = (const bf16x8*)(x2 + (size_t)(row0 + lm) * 128 + quad * 8);
        bf16x8 af[4];
        #pragma unroll
        for (int s = 0; s < 4; s++) af[s] = xr[s * 4];
        f32x4 acc[4];
        #pragma unroll
        for (int nt = 0; nt < 4; nt++) acc[nt] = (f32x4){0.f, 0.f, 0.f, 0.f};
        #pragma unroll
        for (int s = 0; s < 4; s++)
            #pragma unroll
            for (int nt = 0; nt < 4; nt++)
                acc[nt] = __builtin_amdgcn_mfma_f32_16x16x32_bf16(af[s], bfr[s][nt],
                                                                  acc[nt], 0, 0, 0);
        float4 dv = *(const float4*)(dinv + row0 + quad * 4);
        float dvv[4] = {dv.x, dv.y, dv.z, dv.w};
        #pragma unroll
        for (int nt = 0; nt < 4; nt++)
            #pragma unroll
            for (int r = 0; r < 4; r++)
                g2[(size_t)(row0 + quad * 4 + r) * 64 + nt * 16 + lm] =
                    f2bf(acc[nt][r] * dvv[r]);
    }
}

// ---------------- gather1: wave-per-node, whole-row coalesced loads -------------------------
// One 64-lane wave owns one dst node; lane owns channels (2*lane, 2*lane+1) as one uint.
// Per edge: ONE coalesced 256 B row load. Edge indices block-loaded 64-wide, shfl-broadcast.
__global__ __launch_bounds__(256) void gather1_kernel(const unsigned short* __restrict__ g1,
                                                      const unsigned short* __restrict__ esrc,
                                                      const int* __restrict__ off,
                                                      const int* __restrict__ cnt,
                                                      const float* __restrict__ dinv,
                                                      const float* __restrict__ b1,
                                                      unsigned short* __restrict__ x2) {
    const int n = blockIdx.x * 4 + (threadIdx.x >> 6);
    if (n >= NN) return;
    const int lane = threadIdx.x & 63;
    const unsigned int* G = (const unsigned int*)g1;   // row stride 64 uints (256 B)
    float2 ps = bf2f(G[(size_t)n * 64 + lane]);        // self-loop (rows pre-scaled dinv[src])
    float a0 = ps.x, a1 = ps.y;
    float c0 = 0.f, c1 = 0.f;                          // second accumulator pair
    const int s0 = off[n], c = cnt[n];
    for (int base = 0; base < c; base += 64) {
        const int m = min(64, c - base);
        int vidx = 0;
        if (lane < m) vidx = esrc[s0 + base + lane];   // one coalesced 128 B index load
        int i = 0;
        for (; i + 3 < m; i += 4) {
            int sA = __shfl(vidx, i);
            int sB = __shfl(vidx, i + 1);
            int sC = __shfl(vidx, i + 2);
            int sD = __shfl(vidx, i + 3);
            unsigned int vA = G[(size_t)sA * 64 + lane];
            unsigned int vB = G[(size_t)sB * 64 + lane];
            unsigned int vC = G[(size_t)sC * 64 + lane];
            unsigned int vD = G[(size_t)sD * 64 + lane];
            float2 pA = bf2f(vA); a0 += pA.x; a1 += pA.y;
            float2 pB = bf2f(vB); c0 += pB.x; c1 += pB.y;
            float2 pC = bf2f(vC); a0 += pC.x; a1 += pC.y;
            float2 pD = bf2f(vD); c0 += pD.x; c1 += pD.y;
        }
        for (; i < m; i++) {
            int sA = __shfl(vidx, i);
            float2 pA = bf2f(G[(size_t)sA * 64 + lane]);
            a0 += pA.x; a1 += pA.y;
        }
    }
    a0 += c0; a1 += c1;
    const float sc = dinv[n];
    const float2 bb = ((const float2*)b1)[lane];
    const float o0 = fmaxf(sc * a0 + bb.x, 0.f);
    const float o1 = fmaxf(sc * a1 + bb.y, 0.f);
    const unsigned int uo = (unsigned int)f2bf(o0) | ((unsigned int)f2bf(o1) << 16);
    ((unsigned int*)x2)[(size_t)n * 64 + lane] = uo;   // 256 B coalesced store
}

// ---------------- gather2: wave-per-node, whole-row (128 B) coalesced loads, fp32 out --------
// Lane owns channel `lane` (1 ushort). Per edge: ONE coalesced 128 B row load.
__global__ __launch_bounds__(256) void gather2_kernel(const unsigned short* __restrict__ g2,
                                                      const unsigned short* __restrict__ esrc,
                                                      const int* __restrict__ off,
                                                      const int* __restrict__ cnt,
                                                      const float* __restrict__ dinv,
                                                      const float* __restrict__ b2,
                                                      float* __restrict__ out) {
    const int n = blockIdx.x * 4 + (threadIdx.x >> 6);
    if (n >= NN) return;
    const int lane = threadIdx.x & 63;
    const unsigned short* G = g2;                      // row stride 64 ushorts (128 B)
    float a0 = __uint_as_float((unsigned int)G[(size_t)n * 64 + lane] << 16);  // self-loop
    float c0 = 0.f;
    const int s0 = off[n], c = cnt[n];
    for (int base = 0; base < c; base += 64) {
        const int m = min(64, c - base);
        int vidx = 0;
        if (lane < m) vidx = esrc[s0 + base + lane];
        int i = 0;
        for (; i + 3 < m; i += 4) {
            int sA = __shfl(vidx, i);
            int sB = __shfl(vidx, i + 1);
            int sC = __shfl(vidx, i + 2);
            int sD = __shfl(vidx, i + 3);
            unsigned short vA = G[(size_t)sA * 64 + lane];
            unsigned short vB = G[(size_t)sB * 64 + lane];
            unsigned short vC = G[(size_t)sC * 64 + lane];
            unsigned short vD = G[(size_t)sD * 64 + lane];
            a0 += __uint_as_float((unsigned int)vA << 16);
            c0 += __uint_as_float((unsigned int)vB << 16);
            a0 += __uint_as_float((unsigned int)vC << 16);
            c0 += __uint_as_float((unsigned int)vD << 16);
        }
        for (; i < m; i++) {
            int sA = __shfl(vidx, i);
            a0 += __uint_as_float((unsigned int)G[(size_t)sA * 64 + lane] << 16);
        }
    }
    a0 += c0;
    const float sc = dinv[n];
    out[(size_t)n * 64 + lane] = sc * a0 + b2[lane];   // 256 B coalesced store
}

extern "C" void kernel_launch(void* const* d_in, const int* in_sizes, int n_in,
                              void* d_out, int out_size, void* d_ws, size_t ws_size,
                              hipStream_t stream) {
    const float* x  = (const float*)d_in[0];
    const int* edges = (const int*)d_in[1];     // [2, NE] int32
    const float* W1 = (const float*)d_in[2];
    const float* b1 = (const float*)d_in[3];
    const float* W2 = (const float*)d_in[4];
    const float* b2 = (const float*)d_in[5];
    const int* src = edges;
    const int* dst = edges + NE;

    // workspace layout (all chunks 16B-aligned)
    int* localOff  = (int*)d_ws;                        // NBLK*200 = 78200, pad 78208
    unsigned int* ebuf = (unsigned int*)(localOff + 78208);   // NBLK*EPB = 800768
    unsigned short* esrc = (unsigned short*)(ebuf + (size_t)NBLK * EPB);  // 800000 u16, pad 800768
    int* cnt       = (int*)(esrc + 800768);             // 50048
    int* off       = cnt + 50048;                       // 50048
    float* dinv    = (float*)(off + 50048);             // 50048
    unsigned short* g1 = (unsigned short*)(dinv + 50048);   // [N][128] bf16 row-major
    unsigned short* x2 = g1 + (size_t)NN * C1;              // [N][128] bf16 row-major
    unsigned short* g2 = g1;                            // alias: g1 dead before mm2
    float* out = (float*)d_out;

    bin_kernel<<<NBLK, 256, 0, stream>>>(src, dst, ebuf, localOff);
    place_kernel<<<NBK, 256, 0, stream>>>(ebuf, localOff, esrc, cnt, off, dinv);

    mm1_kernel<<<MMB, 256, 0, stream>>>(x, W1, dinv, g1);
    gather1_kernel<<<GB, 256, 0, stream>>>(g1, esrc, off, cnt, dinv, b1, x2);

    mm2_kernel<<<MMB, 256, 0, stream>>>(x2, W2, dinv, g2);
    gather2_kernel<<<GB, 256, 0, stream>>>(g2, esrc, off, cnt, dinv, b2, out);
}